// Round 11
// baseline (405.192 us; speedup 1.0000x reference)
//
#include <hip/hip_runtime.h>
#include <cstdint>
#include <cstddef>

#define LSEQ 2048
#define NB   4
#define DMODEL 1024
#define DINNER 2048
#define NST  16
#define TT   64    // scan LDS time-tile
#define CH   128   // scan chunk length == GEMM tile height
#define SCH  (LSEQ / CH)   // 16 chunks
#define NBD  512           // NB * DINNER/16

typedef short bf16x8 __attribute__((ext_vector_type(8)));
typedef float f32x4  __attribute__((ext_vector_type(4)));

__device__ __forceinline__ float siluf(float x) { return x / (1.f + __expf(-x)); }

__device__ __forceinline__ unsigned short f2bf(float f) {
    unsigned u = __float_as_uint(f);
    u += 0x7FFF + ((u >> 16) & 1);     // round-to-nearest-even
    return (unsigned short)(u >> 16);
}
__device__ __forceinline__ float bf2f(unsigned short h) {
    return __uint_as_float(((unsigned)h) << 16);
}
__device__ __forceinline__ void gload_lds16(const void* g, void* l) {
    __builtin_amdgcn_global_load_lds(
        (const __attribute__((address_space(1))) unsigned int*)g,
        (__attribute__((address_space(3))) unsigned int*)l, 16, 0, 0);
}

template <int CTRL>
__device__ __forceinline__ float dpp_ror(float v) {
    return __int_as_float(__builtin_amdgcn_update_dpp(
        0, __float_as_int(v), CTRL, 0xf, 0xf, false));
}

// ---------------- fused RMSNorm + bf16 convert ----------------
__global__ __launch_bounds__(256) void rmsnorm_cvt_k(const float* __restrict__ x,
                                                     const float* __restrict__ nw,
                                                     unsigned short* __restrict__ o) {
    int row = blockIdx.x, t = threadIdx.x;
    float4 v = ((const float4*)(x + (size_t)row * DMODEL))[t];
    float s = v.x * v.x + v.y * v.y + v.z * v.z + v.w * v.w;
#pragma unroll
    for (int m = 32; m >= 1; m >>= 1) s += __shfl_xor(s, m);
    __shared__ float wsum[4];
    __shared__ float sinv;
    if ((t & 63) == 0) wsum[t >> 6] = s;
    __syncthreads();
    if (t == 0) {
        float tot = wsum[0] + wsum[1] + wsum[2] + wsum[3];
        sinv = rsqrtf(tot * (1.f / (float)DMODEL) + 1e-6f);
    }
    __syncthreads();
    float iv = sinv;
    float4 w = ((const float4*)nw)[t];
    ushort4 ov;
    ov.x = f2bf(v.x * iv * w.x); ov.y = f2bf(v.y * iv * w.y);
    ov.z = f2bf(v.z * iv * w.z); ov.w = f2bf(v.w * iv * w.w);
    ((ushort4*)(o + (size_t)row * DMODEL))[t] = ov;
}

// ---------------- fused weight conversions (4 matrices, 1 launch) ----------------
__global__ __launch_bounds__(256) void cvt_all_k(const float* __restrict__ s0, const float* __restrict__ s1,
                                                 const float* __restrict__ s2, const float* __restrict__ s3,
                                                 unsigned short* __restrict__ q0, unsigned short* __restrict__ q1,
                                                 unsigned short* __restrict__ q2, unsigned short* __restrict__ q3) {
    int i = blockIdx.x * 256 + threadIdx.x;
    const float* s; unsigned short* d; int off;
    if (i < 1048576)       { s = s0; d = q0; off = i; }
    else if (i < 1572864)  { s = s1; d = q1; off = i - 1048576; }
    else if (i < 1622016)  { s = s2; d = q2; off = i - 1572864; }
    else if (i < 1654784)  { s = s3; d = q3; off = i - 1622016; }
    else return;
    float4 v = ((const float4*)s)[off];
    ushort4 o;
    o.x = f2bf(v.x); o.y = f2bf(v.y); o.z = f2bf(v.z); o.w = f2bf(v.w);
    ((ushort4*)d)[off] = o;
}

// ---------------- bf16 MFMA NT GEMM: 3-buffer depth-2 prefetch + XOR swizzle ----------------
// LDS chunk (r, cb) holds global chunk (r, cb ^ (r&7)); reads XOR kk with ((rA&7)<<3).
// Depth-2: STAGE(kt+2) issued at iter kt; steady-state wait vmcnt(16) = 2 stages in flight.
// EPI 0: split store: col<2048 -> f32 Cv (ur), col>=2048 -> bf16 C2 (z)  (in_proj)
// EPI 1: softplus(acc+bias)*mask -> f32 store                            (dt_proj)
// EPI 2: residual + mask*acc -> f32; skipped tiles copy residual         (out_proj)
// EPI 3: col<64 -> bf16 aux (dtr); 64<=col<96 -> f32 Cv (xdbl, ld96)     (x_proj)
template <int EPI>
__global__ __launch_bounds__(256) void gemm_bf16(
    const unsigned short* __restrict__ A, int lda,
    const unsigned short* __restrict__ W, int ldw,
    void* __restrict__ Cv, void* __restrict__ C2v, int ldc,
    int M, int N, int K, int nbx,
    const float* __restrict__ bias,
    const float* __restrict__ residual,
    unsigned short* __restrict__ aux,
    const int* __restrict__ lengths) {
    __shared__ __align__(16) unsigned short As[3][128 * 64];   // 48 KB
    __shared__ __align__(16) unsigned short Bs[3][128 * 64];   // 48 KB
    const int bid = blockIdx.x;
    const int bx = bid % nbx, by = bid / nbx;
    const int row0 = by * 128, col0 = bx * 128;
    const int t = threadIdx.x;

    // row-tile skip: rows [row0,row0+128) all masked -> outputs never consumed
    const int len0 = lengths[row0 >> 11];
    if ((row0 & (LSEQ - 1)) >= len0) {
        if (EPI == 2) {
            float* C = (float*)Cv;
#pragma unroll
            for (int i = 0; i < 16; ++i) {
                int lin = i * 256 + t;                  // 4096 float4 = 128x128
                int r = lin >> 5, c = (lin & 31) << 2;
                *(float4*)(C + (size_t)(row0 + r) * ldc + col0 + c) =
                    *(const float4*)(residual + (size_t)(row0 + r) * ldc + col0 + c);
            }
        }
        return;
    }

    const int lane = t & 63;
    const int w = t >> 6;
    const int wr = w >> 1, wc = w & 1;

    f32x4 acc[4][4];
#pragma unroll
    for (int m = 0; m < 4; ++m)
#pragma unroll
        for (int n = 0; n < 4; ++n) acc[m][n] = f32x4{0.f, 0.f, 0.f, 0.f};

    const int rA = lane & 15;
    const int kH = (lane >> 4) << 3;
    const int NT = K >> 6;
    const int swzR = (rA & 7) << 3;      // read-side XOR (element units)

    // stage one 128x64 K-tile pair into buffer `sel`; source pre-swizzled
    auto STAGE = [&](int sel, int k0) {
#pragma unroll
        for (int it = 0; it < 4; ++it) {
            int c = it * 256 + t;
            int r = c >> 3;
            int cc = ((c & 7) ^ (r & 7)) << 3;           // pre-swizzled source chunk
            gload_lds16(A + (size_t)(row0 + r) * lda + k0 + cc, &As[sel][c << 3]);
            int wrow = col0 + r; if (wrow >= N) wrow = N - 1;   // clamp (x_proj N=96)
            gload_lds16(W + (size_t)wrow * ldw + k0 + cc, &Bs[sel][c << 3]);
        }
    };

    STAGE(0, 0);
    if (NT > 1) STAGE(1, 64);
    for (int kt = 0; kt < NT; ++kt) {
        const int cur = kt % 3;
        if (kt + 2 < NT) STAGE((kt + 2) % 3, (kt + 2) << 6);
        __builtin_amdgcn_sched_barrier(0);
        const int rem = NT - 1 - kt;
        if (rem >= 2)      { asm volatile("s_waitcnt vmcnt(16)" ::: "memory"); }
        else if (rem == 1) { asm volatile("s_waitcnt vmcnt(8)" ::: "memory"); }
        else               { asm volatile("s_waitcnt vmcnt(0)" ::: "memory"); }
        __builtin_amdgcn_sched_barrier(0);
        __builtin_amdgcn_s_barrier();
        __builtin_amdgcn_sched_barrier(0);
#pragma unroll
        for (int ks = 0; ks < 2; ++ks) {
            const int kkS = (ks * 32 + kH) ^ swzR;       // swizzled read offset
            bf16x8 af[4], bfr[4];
#pragma unroll
            for (int m = 0; m < 4; ++m)
                af[m] = *(const bf16x8*)&As[cur][(wr * 64 + m * 16 + rA) * 64 + kkS];
#pragma unroll
            for (int n = 0; n < 4; ++n)
                bfr[n] = *(const bf16x8*)&Bs[cur][(wc * 64 + n * 16 + rA) * 64 + kkS];
#pragma unroll
            for (int m = 0; m < 4; ++m)
#pragma unroll
                for (int n = 0; n < 4; ++n)
                    acc[m][n] = __builtin_amdgcn_mfma_f32_16x16x32_bf16(
                        af[m], bfr[n], acc[m][n], 0, 0, 0);
        }
        __builtin_amdgcn_sched_barrier(0);
        asm volatile("s_waitcnt lgkmcnt(0)" ::: "memory");
        __builtin_amdgcn_s_barrier();
        __builtin_amdgcn_sched_barrier(0);
    }

    const int cl = lane & 15, rg = lane >> 4;
#pragma unroll
    for (int m = 0; m < 4; ++m) {
#pragma unroll
        for (int j = 0; j < 4; ++j) {
            const int row = row0 + wr * 64 + m * 16 + rg * 4 + j;
            float msk = 1.f;
            if (EPI == 1 || EPI == 2) {
                msk = ((row & (LSEQ - 1)) < len0) ? 1.f : 0.f;
            }
#pragma unroll
            for (int n = 0; n < 4; ++n) {
                const int col = col0 + wc * 64 + n * 16 + cl;
                float v = acc[m][n][j];
                if (EPI == 0) {
                    if (col < DINNER) ((float*)Cv)[(size_t)row * DINNER + col] = v;
                    else ((unsigned short*)C2v)[(size_t)row * DINNER + col - DINNER] = f2bf(v);
                } else if (EPI == 1) {
                    v += bias[col];
                    v = (v > 20.f) ? v : log1pf(__expf(v));
                    ((float*)Cv)[(size_t)row * ldc + col] = v * msk;
                } else if (EPI == 2) {
                    ((float*)Cv)[(size_t)row * ldc + col] =
                        residual[(size_t)row * ldc + col] + msk * v;
                } else {  // EPI 3
                    if (col < 64) aux[(size_t)row * 64 + col] = f2bf(v);
                    else if (col < 96) ((float*)Cv)[(size_t)row * 96 + col] = v;
                }
            }
        }
    }
}

// ---------------- causal depthwise conv (K=4) + SiLU + mask -> bf16 ----------------
// masked blocks: zero-fill only up to roundup128(len) (rows scan actually reads)
__global__ __launch_bounds__(256) void conv_silu_k(const float* __restrict__ ur,
                                                   const float* __restrict__ cw,
                                                   const int* __restrict__ lengths,
                                                   unsigned short* __restrict__ u) {
    const int g = blockIdx.x;              // NB * 512
    const int b = g >> 9;
    const int rem = g & 511;
    const int l0 = (rem >> 1) << 3;
    const int d4 = (rem & 1) * 1024 + threadIdx.x * 4;
    const int len = lengths[b];
    const size_t rb = (size_t)b * LSEQ;
    if (l0 >= len) {
        const int lenUp = (len + CH - 1) & ~(CH - 1);
        if (l0 < lenUp) {
            ushort4 z4 = {0, 0, 0, 0};
#pragma unroll
            for (int i = 0; i < 8; ++i)
                *(ushort4*)(u + (rb + l0 + i) * DINNER + d4) = z4;
        }
        return;
    }
    float4 wq[4];
#pragma unroll
    for (int c = 0; c < 4; ++c) wq[c] = *(const float4*)(cw + 4 * (d4 + c));
    const float4 zero4 = {0.f, 0.f, 0.f, 0.f};
    float4 xm3 = (l0 - 3 >= 0 && l0 - 3 < len) ? *(const float4*)(ur + (rb + l0 - 3) * DINNER + d4) : zero4;
    float4 xm2 = (l0 - 2 >= 0 && l0 - 2 < len) ? *(const float4*)(ur + (rb + l0 - 2) * DINNER + d4) : zero4;
    float4 xm1 = (l0 - 1 >= 0 && l0 - 1 < len) ? *(const float4*)(ur + (rb + l0 - 1) * DINNER + d4) : zero4;
#pragma unroll
    for (int i = 0; i < 8; ++i) {
        const int l = l0 + i;
        const bool act = l < len;
        float4 x0 = act ? *(const float4*)(ur + (rb + l) * DINNER + d4) : zero4;
        float a0 = wq[0].x * xm3.x + wq[0].y * xm2.x + wq[0].z * xm1.x + wq[0].w * x0.x;
        float a1 = wq[1].x * xm3.y + wq[1].y * xm2.y + wq[1].z * xm1.y + wq[1].w * x0.y;
        float a2 = wq[2].x * xm3.z + wq[2].y * xm2.z + wq[2].z * xm1.z + wq[2].w * x0.z;
        float a3 = wq[3].x * xm3.w + wq[3].y * xm2.w + wq[3].z * xm1.w + wq[3].w * x0.w;
        ushort4 ov;
        ov.x = f2bf(act ? siluf(a0) : 0.f);
        ov.y = f2bf(act ? siluf(a1) : 0.f);
        ov.z = f2bf(act ? siluf(a2) : 0.f);
        ov.w = f2bf(act ? siluf(a3) : 0.f);
        *(ushort4*)(u + (rb + l) * DINNER + d4) = ov;
        xm3 = xm2; xm2 = xm1; xm1 = x0;
    }
}

// ---------------- scan phase 1: per-chunk local scan (h_in = 0) ----------------
__global__ __launch_bounds__(256) void scan_p1(const float* __restrict__ dlt,
                                               const unsigned short* __restrict__ uy,
                                               const float* __restrict__ xdbl,
                                               const float* __restrict__ A_log,
                                               const int* __restrict__ lengths,
                                               float* __restrict__ hloc,
                                               float* __restrict__ sumd) {
    __shared__ float2 sDU[TT][18];   // {delta, delta*u}; padded stride
    __shared__ float  sB[TT][20];
    const int t = threadIdx.x;
    const int s = blockIdx.x >> 9;
    const int bd = blockIdx.x & (NBD - 1);
    const int b = bd >> 7;
    const int d0 = (bd & 127) << 4;
    const int n = t & 15, ch = t >> 4;
    const size_t hidx = ((size_t)bd * SCH + s) * 256 + t;
    if (s * CH >= lengths[b]) {          // fully masked chunk: exact identity
        hloc[hidx] = 0.f;
        if (n == 0) sumd[(bd * SCH + s) * 16 + ch] = 0.f;
        return;
    }
    const int lr = t >> 2, lq = (t & 3) << 2;
    const int d = d0 + ch;
    const float Av2 = -__expf(A_log[d * NST + n]) * 1.44269504f;
    float h = 0.f, sd = 0.f;
    const size_t base = (size_t)b * LSEQ + (size_t)s * CH;

    for (int l0 = 0; l0 < CH; l0 += TT) {
        const size_t row = base + l0 + lr;
        float4 dv = *(const float4*)(dlt + row * DINNER + d0 + lq);
        ushort4 uv = *(const ushort4*)(uy + row * DINNER + d0 + lq);
        float4 bv = *(const float4*)(xdbl + row * 96 + 64 + lq);
        float4 w0 = {dv.x, dv.x * bf2f(uv.x), dv.y, dv.y * bf2f(uv.y)};
        float4 w1 = {dv.z, dv.z * bf2f(uv.z), dv.w, dv.w * bf2f(uv.w)};
        *(float4*)&sDU[lr][lq]     = w0;
        *(float4*)&sDU[lr][lq + 2] = w1;
        *(float4*)&sB[lr][lq] = bv;
        __syncthreads();
#pragma unroll 16
        for (int r = 0; r < TT; ++r) {
            float2 ddu = sDU[r][ch];
            float Bn = sB[r][n];
            float dA = __builtin_amdgcn_exp2f(ddu.x * Av2);
            h = fmaf(dA, h, ddu.y * Bn);
            sd += ddu.x;
        }
        __syncthreads();
    }
    hloc[hidx] = h;
    if (n == 0) sumd[(bd * SCH + s) * 16 + ch] = sd;
}

// ---------------- scan phase 2: sequential chunk fix-up + h_last ----------------
__global__ __launch_bounds__(256) void scan_p2(const float* __restrict__ hloc,
                                               const float* __restrict__ sumd,
                                               const float* __restrict__ A_log,
                                               float* __restrict__ hin,
                                               float* __restrict__ out_h) {
    const int t = threadIdx.x;
    const int bd = blockIdx.x;
    const int b = bd >> 7;
    const int d = ((bd & 127) << 4) + (t >> 4);
    const int n = t & 15;
    const float Av2 = -__expf(A_log[d * NST + n]) * 1.44269504f;
    float h = 0.f;
#pragma unroll
    for (int s = 0; s < SCH; ++s) {
        const size_t idx = ((size_t)bd * SCH + s) * 256 + t;
        hin[idx] = h;
        float P = __builtin_amdgcn_exp2f(Av2 * sumd[(bd * SCH + s) * 16 + (t >> 4)]);
        h = fmaf(P, h, hloc[idx]);
    }
    out_h[((size_t)(b * DINNER + d)) * NST + n] = h;
}

// ---------------- scan phase 3: replay chunk from h_in, produce gated y ----------------
__global__ __launch_bounds__(256) void scan_p3(const float* __restrict__ dlt,
                                               const unsigned short* __restrict__ zb,  // bf16 z
                                               unsigned short* uy,
                                               const float* __restrict__ xdbl,
                                               const float* __restrict__ A_log,
                                               const float* __restrict__ D_skip,
                                               const int* __restrict__ lengths,
                                               const float* __restrict__ hin) {
    __shared__ float2 sDU[TT][18];   // {delta, delta*u}
    __shared__ float2 sBC[TT][18];   // {B, C}
    __shared__ float  sY[TT][16];
    const int t = threadIdx.x;
    const int s = blockIdx.x >> 9;
    const int bd = blockIdx.x & (NBD - 1);
    const int b = bd >> 7;
    const int d0 = (bd & 127) << 4;
    if (s * CH >= lengths[b]) return;    // fully masked chunk: y never consumed
    const int lr = t >> 2, lq = (t & 3) << 2;
    const int ch = t >> 4, n = t & 15;
    const int d = d0 + ch;
    const float Av2 = -__expf(A_log[d * NST + n]) * 1.44269504f;
    const float4 Dv4 = *(const float4*)(D_skip + d0 + lq);
    float h = hin[((size_t)bd * SCH + s) * 256 + t];
    const size_t base = (size_t)b * LSEQ + (size_t)s * CH;

    for (int l0 = 0; l0 < CH; l0 += TT) {
        const size_t row = base + l0 + lr;
        float4 dv = *(const float4*)(dlt + row * DINNER + d0 + lq);
        ushort4 uv = *(const ushort4*)(uy + row * DINNER + d0 + lq);
        ushort4 zu = *(const ushort4*)(zb + row * DINNER + d0 + lq);
        float4 bv = *(const float4*)(xdbl + row * 96 + 64 + lq);
        float4 cv = *(const float4*)(xdbl + row * 96 + 80 + lq);
        const float uf0 = bf2f(uv.x), uf1 = bf2f(uv.y), uf2 = bf2f(uv.z), uf3 = bf2f(uv.w);
        float4 w0 = {dv.x, dv.x * uf0, dv.y, dv.y * uf1};
        float4 w1 = {dv.z, dv.z * uf2, dv.w, dv.w * uf3};
        *(float4*)&sDU[lr][lq]     = w0;
        *(float4*)&sDU[lr][lq + 2] = w1;
        float4 e0 = {bv.x, cv.x, bv.y, cv.y};
        float4 e1 = {bv.z, cv.z, bv.w, cv.w};
        *(float4*)&sBC[lr][lq]     = e0;
        *(float4*)&sBC[lr][lq + 2] = e1;
        __syncthreads();

#pragma unroll 16
        for (int r = 0; r < TT; ++r) {
            float2 ddu = sDU[r][ch];
            float2 bc  = sBC[r][n];
            float dA = __builtin_amdgcn_exp2f(ddu.x * Av2);
            h = fmaf(dA, h, ddu.y * bc.x);
            float p = h * bc.y;
            p += dpp_ror<0x128>(p);
            p += dpp_ror<0x124>(p);
            p += dpp_ror<0x122>(p);
            p += dpp_ror<0x121>(p);
            if (n == 0) sY[r][ch] = p;
        }
        __syncthreads();

        float4 yv = *(const float4*)&sY[lr][lq];
        ushort4 ov;
        ov.x = f2bf(fmaf(uf0, Dv4.x, yv.x) * siluf(bf2f(zu.x)));
        ov.y = f2bf(fmaf(uf1, Dv4.y, yv.y) * siluf(bf2f(zu.y)));
        ov.z = f2bf(fmaf(uf2, Dv4.z, yv.z) * siluf(bf2f(zu.z)));
        ov.w = f2bf(fmaf(uf3, Dv4.w, yv.w) * siluf(bf2f(zu.w)));
        *(ushort4*)(uy + row * DINNER + d0 + lq) = ov;
        __syncthreads();
    }
}

extern "C" void kernel_launch(void* const* d_in, const int* in_sizes, int n_in,
                              void* d_out, int out_size, void* d_ws, size_t ws_size,
                              hipStream_t stream) {
    const float* hs        = (const float*)d_in[0];
    const int*   lengths   = (const int*)d_in[1];
    const float* norm_w    = (const float*)d_in[2];
    const float* in_proj_w = (const float*)d_in[3];
    const float* conv_w    = (const float*)d_in[4];
    const float* x_proj_w  = (const float*)d_in[5];
    const float* dt_proj_w = (const float*)d_in[6];
    const float* dt_proj_b = (const float*)d_in[7];
    const float* A_log     = (const float*)d_in[8];
    const float* D_skip    = (const float*)d_in[9];
    const float* out_proj_w= (const float*)d_in[10];

    float* out = (float*)d_out;

    const int M = NB * LSEQ;                                            // 8192
    float* ur = (float*)d_ws;                                           // 8192x2048 f32 (64MB): u_raw -> dlt
    unsigned short* zb = (unsigned short*)(ur + (size_t)M * DINNER);    // 8192x2048 bf16 (32MB): z
    unsigned short* u_bf = zb + (size_t)M * DINNER;                     // 8192x2048 bf16 (32MB): u -> y
    float* xdbl = (float*)(u_bf + (size_t)M * DINNER);                  // 8192x96 f32 (3MB)
    unsigned short* w_in  = (unsigned short*)(xdbl + (size_t)M * 96);   // 4096x1024 (8MB)
    unsigned short* w_out = w_in + (size_t)4096 * 1024;                 // 1024x2048 (4MB)
    unsigned short* w_x   = w_out + (size_t)1024 * 2048;                // 96x2048
    unsigned short* w_dt  = w_x + (size_t)96 * 2048;                    // 2048x64
    unsigned short* dtr   = w_dt + (size_t)2048 * 64;                   // 8192x64 bf16 (1MB)
    float* hin            = (float*)(dtr + (size_t)M * 64);             // 512*16*256 f32 (8MB)
    unsigned short* xn_bf = u_bf;          // alias: dead once conv overwrites it
    float* dlt  = ur;                      // alias: ur dead after conv
    float* hloc = (float*)w_in;            // alias: w_in dead after in_proj (8MB exact)
    float* sumd = (float*)dtr;             // alias: dtr dead after dt_proj

    // 1. fused RMSNorm->bf16 + fused weight conversions (1 launch)
    rmsnorm_cvt_k<<<M, 256, 0, stream>>>(hs, norm_w, xn_bf);
    cvt_all_k<<<6464, 256, 0, stream>>>(in_proj_w, out_proj_w, x_proj_w, dt_proj_w,
                                        w_in, w_out, w_x, w_dt);

    // 2. in_proj (bf16 MFMA depth-2+swz, row-skip): ur f32 | z bf16  (8192x4096, K=1024)
    gemm_bf16<0><<<(4096 / 128) * (M / 128), 256, 0, stream>>>(
        xn_bf, DMODEL, w_in, DMODEL, ur, zb, DINNER, M, 4096, DMODEL, 4096 / 128,
        nullptr, nullptr, nullptr, lengths);

    // 3. causal depthwise conv + silu + mask -> u (bf16); zero-fill trimmed to roundup128
    conv_silu_k<<<NB * 512, 256, 0, stream>>>(ur, conv_w, lengths, u_bf);

    // 4. x_proj (bf16 MFMA depth-2+swz, row-skip): B,C -> xdbl f32; dt_r -> dtr bf16 (fused)
    gemm_bf16<3><<<1 * (M / 128), 256, 0, stream>>>(
        u_bf, DINNER, w_x, DINNER, xdbl, nullptr, 96, M, 96, DINNER, 1,
        nullptr, nullptr, dtr, lengths);

    // 5. dt_proj (bf16 MFMA+swz, row-skip) + softplus + mask -> delta f32 (over dead ur)
    gemm_bf16<1><<<(DINNER / 128) * (M / 128), 256, 0, stream>>>(
        dtr, 64, w_dt, 64, dlt, nullptr, DINNER, M, DINNER, 64, DINNER / 128,
        dt_proj_b, nullptr, nullptr, lengths);

    // 6. chunked selective scan (3 phases, chunk-skip); h_last -> tail of d_out
    {
        float* hlast = out + (size_t)M * DMODEL;
        scan_p1<<<NBD * SCH, 256, 0, stream>>>(dlt, u_bf, xdbl, A_log, lengths, hloc, sumd);
        scan_p2<<<NBD, 256, 0, stream>>>(hloc, sumd, A_log, hin, hlast);
        scan_p3<<<NBD * SCH, 256, 0, stream>>>(dlt, zb, u_bf, xdbl, A_log, D_skip, lengths, hin);
    }

    // 7. out_proj (bf16 MFMA depth-2+swz, row-skip -> residual copy) + residual + mask -> d_out
    gemm_bf16<2><<<(DMODEL / 128) * (M / 128), 256, 0, stream>>>(
        u_bf, DINNER, w_out, DINNER, out, nullptr, DMODEL, M, DMODEL, DINNER, DMODEL / 128,
        nullptr, hs, nullptr, lengths);
}

// Round 12
// 331.970 us; speedup vs baseline: 1.2206x; 1.2206x over previous
//
#include <hip/hip_runtime.h>
#include <cstdint>
#include <cstddef>

#define LSEQ 2048
#define NB   4
#define DMODEL 1024
#define DINNER 2048
#define NST  16
#define TT   64    // scan LDS time-tile
#define CH   128   // scan chunk length == GEMM tile height
#define SCH  (LSEQ / CH)   // 16 chunks
#define NBD  512           // NB * DINNER/16

typedef short bf16x8 __attribute__((ext_vector_type(8)));
typedef float f32x4  __attribute__((ext_vector_type(4)));

__device__ __forceinline__ float siluf(float x) { return x / (1.f + __expf(-x)); }

__device__ __forceinline__ unsigned short f2bf(float f) {
    unsigned u = __float_as_uint(f);
    u += 0x7FFF + ((u >> 16) & 1);     // round-to-nearest-even
    return (unsigned short)(u >> 16);
}
__device__ __forceinline__ float bf2f(unsigned short h) {
    return __uint_as_float(((unsigned)h) << 16);
}
__device__ __forceinline__ void gload_lds16(const void* g, void* l) {
    __builtin_amdgcn_global_load_lds(
        (const __attribute__((address_space(1))) unsigned int*)g,
        (__attribute__((address_space(3))) unsigned int*)l, 16, 0, 0);
}

template <int CTRL>
__device__ __forceinline__ float dpp_ror(float v) {
    return __int_as_float(__builtin_amdgcn_update_dpp(
        0, __float_as_int(v), CTRL, 0xf, 0xf, false));
}

// ---------------- fused RMSNorm + bf16 convert ----------------
__global__ __launch_bounds__(256) void rmsnorm_cvt_k(const float* __restrict__ x,
                                                     const float* __restrict__ nw,
                                                     unsigned short* __restrict__ o) {
    int row = blockIdx.x, t = threadIdx.x;
    float4 v = ((const float4*)(x + (size_t)row * DMODEL))[t];
    float s = v.x * v.x + v.y * v.y + v.z * v.z + v.w * v.w;
#pragma unroll
    for (int m = 32; m >= 1; m >>= 1) s += __shfl_xor(s, m);
    __shared__ float wsum[4];
    __shared__ float sinv;
    if ((t & 63) == 0) wsum[t >> 6] = s;
    __syncthreads();
    if (t == 0) {
        float tot = wsum[0] + wsum[1] + wsum[2] + wsum[3];
        sinv = rsqrtf(tot * (1.f / (float)DMODEL) + 1e-6f);
    }
    __syncthreads();
    float iv = sinv;
    float4 w = ((const float4*)nw)[t];
    ushort4 ov;
    ov.x = f2bf(v.x * iv * w.x); ov.y = f2bf(v.y * iv * w.y);
    ov.z = f2bf(v.z * iv * w.z); ov.w = f2bf(v.w * iv * w.w);
    ((ushort4*)(o + (size_t)row * DMODEL))[t] = ov;
}

// ---------------- fused weight conversions (4 matrices, 1 launch) ----------------
__global__ __launch_bounds__(256) void cvt_all_k(const float* __restrict__ s0, const float* __restrict__ s1,
                                                 const float* __restrict__ s2, const float* __restrict__ s3,
                                                 unsigned short* __restrict__ q0, unsigned short* __restrict__ q1,
                                                 unsigned short* __restrict__ q2, unsigned short* __restrict__ q3) {
    int i = blockIdx.x * 256 + threadIdx.x;
    const float* s; unsigned short* d; int off;
    if (i < 1048576)       { s = s0; d = q0; off = i; }
    else if (i < 1572864)  { s = s1; d = q1; off = i - 1048576; }
    else if (i < 1622016)  { s = s2; d = q2; off = i - 1572864; }
    else if (i < 1654784)  { s = s3; d = q3; off = i - 1622016; }
    else return;
    float4 v = ((const float4*)s)[off];
    ushort4 o;
    o.x = f2bf(v.x); o.y = f2bf(v.y); o.z = f2bf(v.z); o.w = f2bf(v.w);
    ((ushort4*)d)[off] = o;
}

// ---------------- bf16 MFMA NT GEMM: single-buffer (32KB LDS, max occupancy) + XOR swizzle ----------------
// LDS chunk (r, cb) holds global chunk (r, cb ^ (r&7)); reads XOR kk with ((rA&7)<<3).
// Plain __syncthreads: compiler inserts its own waitcnt; cross-block TLP (up to 5 blocks/CU)
// hides the barrier drain (m97/m114 pattern — confirmed by round-11's occupancy regression).
// EPI 0: split store: col<2048 -> f32 Cv (ur), col>=2048 -> bf16 C2 (z)  (in_proj)
// EPI 1: softplus(acc+bias)*mask -> f32 store                            (dt_proj)
// EPI 2: residual + mask*acc -> f32; skipped tiles copy residual         (out_proj)
// EPI 3: col<64 -> bf16 aux (dtr); 64<=col<96 -> f32 Cv (xdbl, ld96)     (x_proj)
template <int EPI>
__global__ __launch_bounds__(256) void gemm_bf16(
    const unsigned short* __restrict__ A, int lda,
    const unsigned short* __restrict__ W, int ldw,
    void* __restrict__ Cv, void* __restrict__ C2v, int ldc,
    int M, int N, int K, int nbx,
    const float* __restrict__ bias,
    const float* __restrict__ residual,
    unsigned short* __restrict__ aux,
    const int* __restrict__ lengths) {
    __shared__ __align__(16) unsigned short As[128 * 64];   // 16 KB
    __shared__ __align__(16) unsigned short Bs[128 * 64];   // 16 KB
    const int bid = blockIdx.x;
    const int bx = bid % nbx, by = bid / nbx;
    const int row0 = by * 128, col0 = bx * 128;
    const int t = threadIdx.x;

    // row-tile skip: rows [row0,row0+128) all masked -> outputs never consumed
    const int len0 = lengths[row0 >> 11];
    if ((row0 & (LSEQ - 1)) >= len0) {
        if (EPI == 2) {
            float* C = (float*)Cv;
#pragma unroll
            for (int i = 0; i < 16; ++i) {
                int lin = i * 256 + t;                  // 4096 float4 = 128x128
                int r = lin >> 5, c = (lin & 31) << 2;
                *(float4*)(C + (size_t)(row0 + r) * ldc + col0 + c) =
                    *(const float4*)(residual + (size_t)(row0 + r) * ldc + col0 + c);
            }
        }
        return;
    }

    const int lane = t & 63;
    const int w = t >> 6;
    const int wr = w >> 1, wc = w & 1;

    f32x4 acc[4][4];
#pragma unroll
    for (int m = 0; m < 4; ++m)
#pragma unroll
        for (int n = 0; n < 4; ++n) acc[m][n] = f32x4{0.f, 0.f, 0.f, 0.f};

    const int rA = lane & 15;
    const int kH = (lane >> 4) << 3;
    const int swzR = (rA & 7) << 3;      // read-side XOR (element units)

    for (int k0 = 0; k0 < K; k0 += 64) {
#pragma unroll
        for (int it = 0; it < 4; ++it) {
            int c = it * 256 + t;
            int r = c >> 3;
            int cc = ((c & 7) ^ (r & 7)) << 3;           // pre-swizzled source chunk
            gload_lds16(A + (size_t)(row0 + r) * lda + k0 + cc, &As[c << 3]);
            int wrow = col0 + r; if (wrow >= N) wrow = N - 1;   // clamp (x_proj N=96)
            gload_lds16(W + (size_t)wrow * ldw + k0 + cc, &Bs[c << 3]);
        }
        __syncthreads();
#pragma unroll
        for (int ks = 0; ks < 2; ++ks) {
            const int kkS = (ks * 32 + kH) ^ swzR;       // swizzled read offset
            bf16x8 af[4], bfr[4];
#pragma unroll
            for (int m = 0; m < 4; ++m)
                af[m] = *(const bf16x8*)&As[(wr * 64 + m * 16 + rA) * 64 + kkS];
#pragma unroll
            for (int n = 0; n < 4; ++n)
                bfr[n] = *(const bf16x8*)&Bs[(wc * 64 + n * 16 + rA) * 64 + kkS];
#pragma unroll
            for (int m = 0; m < 4; ++m)
#pragma unroll
                for (int n = 0; n < 4; ++n)
                    acc[m][n] = __builtin_amdgcn_mfma_f32_16x16x32_bf16(
                        af[m], bfr[n], acc[m][n], 0, 0, 0);
        }
        __syncthreads();
    }

    const int cl = lane & 15, rg = lane >> 4;
#pragma unroll
    for (int m = 0; m < 4; ++m) {
#pragma unroll
        for (int j = 0; j < 4; ++j) {
            const int row = row0 + wr * 64 + m * 16 + rg * 4 + j;
            float msk = 1.f;
            if (EPI == 1 || EPI == 2) {
                msk = ((row & (LSEQ - 1)) < len0) ? 1.f : 0.f;
            }
#pragma unroll
            for (int n = 0; n < 4; ++n) {
                const int col = col0 + wc * 64 + n * 16 + cl;
                float v = acc[m][n][j];
                if (EPI == 0) {
                    if (col < DINNER) ((float*)Cv)[(size_t)row * DINNER + col] = v;
                    else ((unsigned short*)C2v)[(size_t)row * DINNER + col - DINNER] = f2bf(v);
                } else if (EPI == 1) {
                    v += bias[col];
                    v = (v > 20.f) ? v : log1pf(__expf(v));
                    ((float*)Cv)[(size_t)row * ldc + col] = v * msk;
                } else if (EPI == 2) {
                    ((float*)Cv)[(size_t)row * ldc + col] =
                        residual[(size_t)row * ldc + col] + msk * v;
                } else {  // EPI 3
                    if (col < 64) aux[(size_t)row * 64 + col] = f2bf(v);
                    else if (col < 96) ((float*)Cv)[(size_t)row * 96 + col] = v;
                }
            }
        }
    }
}

// ---------------- causal depthwise conv (K=4) + SiLU + mask -> bf16 ----------------
// masked blocks: zero-fill only up to roundup128(len) (rows scan actually reads)
__global__ __launch_bounds__(256) void conv_silu_k(const float* __restrict__ ur,
                                                   const float* __restrict__ cw,
                                                   const int* __restrict__ lengths,
                                                   unsigned short* __restrict__ u) {
    const int g = blockIdx.x;              // NB * 512
    const int b = g >> 9;
    const int rem = g & 511;
    const int l0 = (rem >> 1) << 3;
    const int d4 = (rem & 1) * 1024 + threadIdx.x * 4;
    const int len = lengths[b];
    const size_t rb = (size_t)b * LSEQ;
    if (l0 >= len) {
        const int lenUp = (len + CH - 1) & ~(CH - 1);
        if (l0 < lenUp) {
            ushort4 z4 = {0, 0, 0, 0};
#pragma unroll
            for (int i = 0; i < 8; ++i)
                *(ushort4*)(u + (rb + l0 + i) * DINNER + d4) = z4;
        }
        return;
    }
    float4 wq[4];
#pragma unroll
    for (int c = 0; c < 4; ++c) wq[c] = *(const float4*)(cw + 4 * (d4 + c));
    const float4 zero4 = {0.f, 0.f, 0.f, 0.f};
    float4 xm3 = (l0 - 3 >= 0 && l0 - 3 < len) ? *(const float4*)(ur + (rb + l0 - 3) * DINNER + d4) : zero4;
    float4 xm2 = (l0 - 2 >= 0 && l0 - 2 < len) ? *(const float4*)(ur + (rb + l0 - 2) * DINNER + d4) : zero4;
    float4 xm1 = (l0 - 1 >= 0 && l0 - 1 < len) ? *(const float4*)(ur + (rb + l0 - 1) * DINNER + d4) : zero4;
#pragma unroll
    for (int i = 0; i < 8; ++i) {
        const int l = l0 + i;
        const bool act = l < len;
        float4 x0 = act ? *(const float4*)(ur + (rb + l) * DINNER + d4) : zero4;
        float a0 = wq[0].x * xm3.x + wq[0].y * xm2.x + wq[0].z * xm1.x + wq[0].w * x0.x;
        float a1 = wq[1].x * xm3.y + wq[1].y * xm2.y + wq[1].z * xm1.y + wq[1].w * x0.y;
        float a2 = wq[2].x * xm3.z + wq[2].y * xm2.z + wq[2].z * xm1.z + wq[2].w * x0.z;
        float a3 = wq[3].x * xm3.w + wq[3].y * xm2.w + wq[3].z * xm1.w + wq[3].w * x0.w;
        ushort4 ov;
        ov.x = f2bf(act ? siluf(a0) : 0.f);
        ov.y = f2bf(act ? siluf(a1) : 0.f);
        ov.z = f2bf(act ? siluf(a2) : 0.f);
        ov.w = f2bf(act ? siluf(a3) : 0.f);
        *(ushort4*)(u + (rb + l) * DINNER + d4) = ov;
        xm3 = xm2; xm2 = xm1; xm1 = x0;
    }
}

// ---------------- scan phase 1: per-chunk local scan (h_in = 0) ----------------
__global__ __launch_bounds__(256) void scan_p1(const float* __restrict__ dlt,
                                               const unsigned short* __restrict__ uy,
                                               const float* __restrict__ xdbl,
                                               const float* __restrict__ A_log,
                                               const int* __restrict__ lengths,
                                               float* __restrict__ hloc,
                                               float* __restrict__ sumd) {
    __shared__ float2 sDU[TT][18];   // {delta, delta*u}; padded stride
    __shared__ float  sB[TT][20];
    const int t = threadIdx.x;
    const int s = blockIdx.x >> 9;
    const int bd = blockIdx.x & (NBD - 1);
    const int b = bd >> 7;
    const int d0 = (bd & 127) << 4;
    const int n = t & 15, ch = t >> 4;
    const size_t hidx = ((size_t)bd * SCH + s) * 256 + t;
    if (s * CH >= lengths[b]) {          // fully masked chunk: exact identity
        hloc[hidx] = 0.f;
        if (n == 0) sumd[(bd * SCH + s) * 16 + ch] = 0.f;
        return;
    }
    const int lr = t >> 2, lq = (t & 3) << 2;
    const int d = d0 + ch;
    const float Av2 = -__expf(A_log[d * NST + n]) * 1.44269504f;
    float h = 0.f, sd = 0.f;
    const size_t base = (size_t)b * LSEQ + (size_t)s * CH;

    for (int l0 = 0; l0 < CH; l0 += TT) {
        const size_t row = base + l0 + lr;
        float4 dv = *(const float4*)(dlt + row * DINNER + d0 + lq);
        ushort4 uv = *(const ushort4*)(uy + row * DINNER + d0 + lq);
        float4 bv = *(const float4*)(xdbl + row * 96 + 64 + lq);
        float4 w0 = {dv.x, dv.x * bf2f(uv.x), dv.y, dv.y * bf2f(uv.y)};
        float4 w1 = {dv.z, dv.z * bf2f(uv.z), dv.w, dv.w * bf2f(uv.w)};
        *(float4*)&sDU[lr][lq]     = w0;
        *(float4*)&sDU[lr][lq + 2] = w1;
        *(float4*)&sB[lr][lq] = bv;
        __syncthreads();
#pragma unroll 16
        for (int r = 0; r < TT; ++r) {
            float2 ddu = sDU[r][ch];
            float Bn = sB[r][n];
            float dA = __builtin_amdgcn_exp2f(ddu.x * Av2);
            h = fmaf(dA, h, ddu.y * Bn);
            sd += ddu.x;
        }
        __syncthreads();
    }
    hloc[hidx] = h;
    if (n == 0) sumd[(bd * SCH + s) * 16 + ch] = sd;
}

// ---------------- scan phase 2: sequential chunk fix-up + h_last ----------------
__global__ __launch_bounds__(256) void scan_p2(const float* __restrict__ hloc,
                                               const float* __restrict__ sumd,
                                               const float* __restrict__ A_log,
                                               float* __restrict__ hin,
                                               float* __restrict__ out_h) {
    const int t = threadIdx.x;
    const int bd = blockIdx.x;
    const int b = bd >> 7;
    const int d = ((bd & 127) << 4) + (t >> 4);
    const int n = t & 15;
    const float Av2 = -__expf(A_log[d * NST + n]) * 1.44269504f;
    float h = 0.f;
#pragma unroll
    for (int s = 0; s < SCH; ++s) {
        const size_t idx = ((size_t)bd * SCH + s) * 256 + t;
        hin[idx] = h;
        float P = __builtin_amdgcn_exp2f(Av2 * sumd[(bd * SCH + s) * 16 + (t >> 4)]);
        h = fmaf(P, h, hloc[idx]);
    }
    out_h[((size_t)(b * DINNER + d)) * NST + n] = h;
}

// ---------------- scan phase 3: replay chunk from h_in, produce gated y ----------------
__global__ __launch_bounds__(256) void scan_p3(const float* __restrict__ dlt,
                                               const unsigned short* __restrict__ zb,  // bf16 z
                                               unsigned short* uy,
                                               const float* __restrict__ xdbl,
                                               const float* __restrict__ A_log,
                                               const float* __restrict__ D_skip,
                                               const int* __restrict__ lengths,
                                               const float* __restrict__ hin) {
    __shared__ float2 sDU[TT][18];   // {delta, delta*u}
    __shared__ float2 sBC[TT][18];   // {B, C}
    __shared__ float  sY[TT][16];
    const int t = threadIdx.x;
    const int s = blockIdx.x >> 9;
    const int bd = blockIdx.x & (NBD - 1);
    const int b = bd >> 7;
    const int d0 = (bd & 127) << 4;
    if (s * CH >= lengths[b]) return;    // fully masked chunk: y never consumed
    const int lr = t >> 2, lq = (t & 3) << 2;
    const int ch = t >> 4, n = t & 15;
    const int d = d0 + ch;
    const float Av2 = -__expf(A_log[d * NST + n]) * 1.44269504f;
    const float4 Dv4 = *(const float4*)(D_skip + d0 + lq);
    float h = hin[((size_t)bd * SCH + s) * 256 + t];
    const size_t base = (size_t)b * LSEQ + (size_t)s * CH;

    for (int l0 = 0; l0 < CH; l0 += TT) {
        const size_t row = base + l0 + lr;
        float4 dv = *(const float4*)(dlt + row * DINNER + d0 + lq);
        ushort4 uv = *(const ushort4*)(uy + row * DINNER + d0 + lq);
        ushort4 zu = *(const ushort4*)(zb + row * DINNER + d0 + lq);
        float4 bv = *(const float4*)(xdbl + row * 96 + 64 + lq);
        float4 cv = *(const float4*)(xdbl + row * 96 + 80 + lq);
        const float uf0 = bf2f(uv.x), uf1 = bf2f(uv.y), uf2 = bf2f(uv.z), uf3 = bf2f(uv.w);
        float4 w0 = {dv.x, dv.x * uf0, dv.y, dv.y * uf1};
        float4 w1 = {dv.z, dv.z * uf2, dv.w, dv.w * uf3};
        *(float4*)&sDU[lr][lq]     = w0;
        *(float4*)&sDU[lr][lq + 2] = w1;
        float4 e0 = {bv.x, cv.x, bv.y, cv.y};
        float4 e1 = {bv.z, cv.z, bv.w, cv.w};
        *(float4*)&sBC[lr][lq]     = e0;
        *(float4*)&sBC[lr][lq + 2] = e1;
        __syncthreads();

#pragma unroll 16
        for (int r = 0; r < TT; ++r) {
            float2 ddu = sDU[r][ch];
            float2 bc  = sBC[r][n];
            float dA = __builtin_amdgcn_exp2f(ddu.x * Av2);
            h = fmaf(dA, h, ddu.y * bc.x);
            float p = h * bc.y;
            p += dpp_ror<0x128>(p);
            p += dpp_ror<0x124>(p);
            p += dpp_ror<0x122>(p);
            p += dpp_ror<0x121>(p);
            if (n == 0) sY[r][ch] = p;
        }
        __syncthreads();

        float4 yv = *(const float4*)&sY[lr][lq];
        ushort4 ov;
        ov.x = f2bf(fmaf(uf0, Dv4.x, yv.x) * siluf(bf2f(zu.x)));
        ov.y = f2bf(fmaf(uf1, Dv4.y, yv.y) * siluf(bf2f(zu.y)));
        ov.z = f2bf(fmaf(uf2, Dv4.z, yv.z) * siluf(bf2f(zu.z)));
        ov.w = f2bf(fmaf(uf3, Dv4.w, yv.w) * siluf(bf2f(zu.w)));
        *(ushort4*)(uy + row * DINNER + d0 + lq) = ov;
        __syncthreads();
    }
}

extern "C" void kernel_launch(void* const* d_in, const int* in_sizes, int n_in,
                              void* d_out, int out_size, void* d_ws, size_t ws_size,
                              hipStream_t stream) {
    const float* hs        = (const float*)d_in[0];
    const int*   lengths   = (const int*)d_in[1];
    const float* norm_w    = (const float*)d_in[2];
    const float* in_proj_w = (const float*)d_in[3];
    const float* conv_w    = (const float*)d_in[4];
    const float* x_proj_w  = (const float*)d_in[5];
    const float* dt_proj_w = (const float*)d_in[6];
    const float* dt_proj_b = (const float*)d_in[7];
    const float* A_log     = (const float*)d_in[8];
    const float* D_skip    = (const float*)d_in[9];
    const float* out_proj_w= (const float*)d_in[10];

    float* out = (float*)d_out;

    const int M = NB * LSEQ;                                            // 8192
    float* ur = (float*)d_ws;                                           // 8192x2048 f32 (64MB): u_raw -> dlt
    unsigned short* zb = (unsigned short*)(ur + (size_t)M * DINNER);    // 8192x2048 bf16 (32MB): z
    unsigned short* u_bf = zb + (size_t)M * DINNER;                     // 8192x2048 bf16 (32MB): u -> y
    float* xdbl = (float*)(u_bf + (size_t)M * DINNER);                  // 8192x96 f32 (3MB)
    unsigned short* w_in  = (unsigned short*)(xdbl + (size_t)M * 96);   // 4096x1024 (8MB)
    unsigned short* w_out = w_in + (size_t)4096 * 1024;                 // 1024x2048 (4MB)
    unsigned short* w_x   = w_out + (size_t)1024 * 2048;                // 96x2048
    unsigned short* w_dt  = w_x + (size_t)96 * 2048;                    // 2048x64
    unsigned short* dtr   = w_dt + (size_t)2048 * 64;                   // 8192x64 bf16 (1MB)
    float* hin            = (float*)(dtr + (size_t)M * 64);             // 512*16*256 f32 (8MB)
    unsigned short* xn_bf = u_bf;          // alias: dead once conv overwrites it
    float* dlt  = ur;                      // alias: ur dead after conv
    float* hloc = (float*)w_in;            // alias: w_in dead after in_proj (8MB exact)
    float* sumd = (float*)dtr;             // alias: dtr dead after dt_proj

    // 1. fused RMSNorm->bf16 + fused weight conversions (1 launch)
    rmsnorm_cvt_k<<<M, 256, 0, stream>>>(hs, norm_w, xn_bf);
    cvt_all_k<<<6464, 256, 0, stream>>>(in_proj_w, out_proj_w, x_proj_w, dt_proj_w,
                                        w_in, w_out, w_x, w_dt);

    // 2. in_proj (bf16 MFMA sbuf+swz, row-skip): ur f32 | z bf16  (8192x4096, K=1024)
    gemm_bf16<0><<<(4096 / 128) * (M / 128), 256, 0, stream>>>(
        xn_bf, DMODEL, w_in, DMODEL, ur, zb, DINNER, M, 4096, DMODEL, 4096 / 128,
        nullptr, nullptr, nullptr, lengths);

    // 3. causal depthwise conv + silu + mask -> u (bf16); zero-fill trimmed to roundup128
    conv_silu_k<<<NB * 512, 256, 0, stream>>>(ur, conv_w, lengths, u_bf);

    // 4. x_proj (bf16 MFMA sbuf+swz, row-skip): B,C -> xdbl f32; dt_r -> dtr bf16 (fused)
    gemm_bf16<3><<<1 * (M / 128), 256, 0, stream>>>(
        u_bf, DINNER, w_x, DINNER, xdbl, nullptr, 96, M, 96, DINNER, 1,
        nullptr, nullptr, dtr, lengths);

    // 5. dt_proj (bf16 MFMA sbuf+swz, row-skip) + softplus + mask -> delta f32 (over dead ur)
    gemm_bf16<1><<<(DINNER / 128) * (M / 128), 256, 0, stream>>>(
        dtr, 64, w_dt, 64, dlt, nullptr, DINNER, M, DINNER, 64, DINNER / 128,
        dt_proj_b, nullptr, nullptr, lengths);

    // 6. chunked selective scan (3 phases, chunk-skip); h_last -> tail of d_out
    {
        float* hlast = out + (size_t)M * DMODEL;
        scan_p1<<<NBD * SCH, 256, 0, stream>>>(dlt, u_bf, xdbl, A_log, lengths, hloc, sumd);
        scan_p2<<<NBD, 256, 0, stream>>>(hloc, sumd, A_log, hin, hlast);
        scan_p3<<<NBD * SCH, 256, 0, stream>>>(dlt, zb, u_bf, xdbl, A_log, D_skip, lengths, hin);
    }

    // 7. out_proj (bf16 MFMA sbuf+swz, row-skip -> residual copy) + residual + mask -> d_out
    gemm_bf16<2><<<(DMODEL / 128) * (M / 128), 256, 0, stream>>>(
        u_bf, DINNER, w_out, DINNER, out, nullptr, DMODEL, M, DMODEL, DINNER, DMODEL / 128,
        nullptr, hs, nullptr, lengths);
}